// Round 3
// baseline (431.055 us; speedup 1.0000x reference)
//
#include <hip/hip_runtime.h>
#include <hip/hip_cooperative_groups.h>

namespace cg = cooperative_groups;

#define DS   256
#define FULL 2048
#define NIMG 8
#define NBLK 1024
#define NTHR 256

// Segment-mean contribution for a 256-long line handled by 256 threads.
// m = 256-bit boundary mask (this wave's 64 bits). Matches reference _seg_means.
__device__ __forceinline__ float seg_fast(float x, bool z, unsigned long long m, int j,
                                          float* s_cs,
                                          unsigned long long* s_msk,
                                          float* s_ws) {
    const int lane = j & 63;
    const int w    = j >> 6;

    // wave-level inclusive cumsum in registers
    float s = x;
    #pragma unroll
    for (int off = 1; off < 64; off <<= 1) {
        float t = __shfl_up(s, off, 64);
        if (lane >= off) s += t;
    }
    if (lane == 63) s_ws[w]  = s;
    if (lane == 0)  s_msk[w] = m;
    __syncthreads();

    float pre = 0.f;
    for (int ww = 0; ww < w; ++ww) pre += s_ws[ww];
    s += pre;
    s_cs[j] = s;

    // prev = last boundary < j ; nxt = first boundary > j
    unsigned long long lo = m & ((1ULL << lane) - 1ULL);
    int prev = -1;
    if (lo) prev = (w << 6) + 63 - __builtin_clzll(lo);
    else {
        for (int ww = w - 1; ww >= 0; --ww) {
            unsigned long long mm = s_msk[ww];
            if (mm) { prev = (ww << 6) + 63 - __builtin_clzll(mm); break; }
        }
    }
    unsigned long long hi = m & ~((2ULL << lane) - 1ULL);
    int nxt = DS;
    if (hi) nxt = (w << 6) + __builtin_ctzll(hi);
    else {
        for (int ww = w + 1; ww < 4; ++ww) {
            unsigned long long mm = s_msk[ww];
            if (mm) { nxt = (ww << 6) + __builtin_ctzll(mm); break; }
        }
    }
    __syncthreads();   // s_cs fully written

    bool valid = (!z) && (prev >= 0) && (nxt < DS);
    if (valid) {
        float cs_j   = s_cs[j];
        float cs_pm1 = (prev > 0) ? s_cs[prev - 1] : 0.f;
        float cs_n   = s_cs[nxt];
        float cs_jm1 = (j > 0) ? s_cs[j - 1] : 0.f;
        return (cs_j - cs_pm1) / (float)(j - prev + 1)
             + (cs_n - cs_jm1) / (float)(nxt - j + 1);
    }
    return 2.f * x;
}

__global__ __launch_bounds__(NTHR, 4) void k_fused(
        const float* __restrict__ x0, const int* __restrict__ x1,
        float* __restrict__ xd, unsigned long long* __restrict__ zm,
        float* __restrict__ yH, float4* __restrict__ out) {
    __shared__ float s_cs[DS];
    __shared__ unsigned long long s_msk[4];
    __shared__ float s_ws[4];
    cg::grid_group grid = cg::this_grid();
    const int j = threadIdx.x;

    // ---- Phase A: gather + horizontal segment means (2 rows per block) ----
    #pragma unroll
    for (int l = 0; l < 2; ++l) {
        int line = (blockIdx.x << 1) | l;            // n*256 + i
        int n = line >> 8, i = line & 255;
        size_t src = ((size_t)(n * FULL + i * 8)) * FULL + (size_t)j * 8;
        float x = x0[src];
        bool  z = (x1[src] == 0);
        unsigned long long m = __ballot(z);
        int d = (line << 8) + j;
        xd[d] = x;
        if ((j & 63) == 0) zm[(line << 2) + (j >> 6)] = m;
        yH[d] = seg_fast(x, z, m, j, s_cs, s_msk, s_ws);
    }
    __threadfence();
    grid.sync();

    // ---- Phase B: vertical segment means (2 columns per block) ----
    #pragma unroll
    for (int l = 0; l < 2; ++l) {
        int line = (blockIdx.x << 1) | l;            // n*256 + c
        int n = line >> 8, c = line & 255;
        int d = (n << 16) + (j << 8) + c;
        float x = xd[d];
        unsigned long long mw = zm[(((n << 8) + j) << 2) + (c >> 6)];
        bool z = (mw >> (c & 63)) & 1ULL;
        unsigned long long m = __ballot(z);
        float r = seg_fast(x, z, m, j, s_cs, s_msk, s_ws);
        yH[d] += r;
    }
    __threadfence();
    grid.sync();

    // ---- Phase C: 8x8 nearest-neighbor upsample, 32 B stores ----
    int tid = blockIdx.x * NTHR + j;
    #pragma unroll
    for (int it = 0; it < 16; ++it) {
        int p  = tid + it * (NBLK * NTHR);   // float4-pair index, 4194304 total
        int g2 = p << 1;
        int j4 = g2 & 511;                   // float4 slot within 2048-wide row
        int r  = g2 >> 9;                    // n*2048 + I
        int I  = r & 2047;
        int n  = r >> 11;
        float v = yH[(n << 16) + ((I >> 3) << 8) + (j4 >> 1)];
        float4 vv = make_float4(v, v, v, v);
        out[g2]     = vv;
        out[g2 + 1] = vv;
    }
}

extern "C" void kernel_launch(void* const* d_in, const int* in_sizes, int n_in,
                              void* d_out, int out_size, void* d_ws, size_t ws_size,
                              hipStream_t stream) {
    const float* x0 = (const float*)d_in[0];
    const int*   x1 = (const int*)d_in[1];
    float4* out = (float4*)d_out;

    // ws layout: xd (2MB) | zm (64KB) | yH (2MB)
    float* xd = (float*)d_ws;
    unsigned long long* zm = (unsigned long long*)(xd + NIMG * DS * DS);
    float* yH = (float*)(zm + NIMG * DS * 4);

    void* args[] = { (void*)&x0, (void*)&x1, (void*)&xd, (void*)&zm, (void*)&yH, (void*)&out };
    hipLaunchCooperativeKernel((void*)k_fused, dim3(NBLK), dim3(NTHR),
                               args, 0, stream);
}

// Round 5
// 84.469 us; speedup vs baseline: 5.1031x; 5.1031x over previous
//
#include <hip/hip_runtime.h>

#define DS   256
#define FULL 2048
#define NIMG 8

typedef float f32x4 __attribute__((ext_vector_type(4)));

// Segment-mean contribution for a 256-long line handled by 256 threads.
// Returns lr+rl (or 2x where invalid), matching the reference _seg_means.
__device__ __forceinline__ float seg_fast(float x, bool z, int j,
                                          float* s_cs,
                                          unsigned long long* s_msk,
                                          float* s_ws) {
    const int lane = j & 63;
    const int w    = j >> 6;
    unsigned long long m = __ballot(z);

    // wave-level inclusive cumsum in registers
    float s = x;
    #pragma unroll
    for (int off = 1; off < 64; off <<= 1) {
        float t = __shfl_up(s, off, 64);
        if (lane >= off) s += t;
    }
    if (lane == 63) s_ws[w]  = s;
    if (lane == 0)  s_msk[w] = m;
    __syncthreads();

    float pre = 0.f;
    for (int ww = 0; ww < w; ++ww) pre += s_ws[ww];
    s += pre;
    s_cs[j] = s;

    // prev = last boundary < j ; nxt = first boundary > j
    unsigned long long lo = m & ((1ULL << lane) - 1ULL);
    int prev = -1;
    if (lo) prev = (w << 6) + 63 - __builtin_clzll(lo);
    else {
        for (int ww = w - 1; ww >= 0; --ww) {
            unsigned long long mm = s_msk[ww];
            if (mm) { prev = (ww << 6) + 63 - __builtin_clzll(mm); break; }
        }
    }
    unsigned long long hi = m & ~((2ULL << lane) - 1ULL);
    int nxt = DS;
    if (hi) nxt = (w << 6) + __builtin_ctzll(hi);
    else {
        for (int ww = w + 1; ww < 4; ++ww) {
            unsigned long long mm = s_msk[ww];
            if (mm) { nxt = (ww << 6) + __builtin_ctzll(mm); break; }
        }
    }
    __syncthreads();   // s_cs fully written

    bool valid = (!z) && (prev >= 0) && (nxt < DS);
    if (valid) {
        float cs_j   = s_cs[j];
        float cs_pm1 = (prev > 0) ? s_cs[prev - 1] : 0.f;
        float cs_n   = s_cs[nxt];
        float cs_jm1 = (j > 0) ? s_cs[j - 1] : 0.f;
        return (cs_j - cs_pm1) / (float)(j - prev + 1)
             + (cs_n - cs_jm1) / (float)(nxt - j + 1);
    }
    return 2.f * x;
}

// K12: blocks 0..2047 = horizontal lines (row-major gather),
//      blocks 2048..4095 = vertical lines (column gather, L3-served).
// Independent outputs yH / yV -> no inter-pass dependency.
__global__ __launch_bounds__(256) void k_seg(const float* __restrict__ x0,
                                             const int* __restrict__ x1,
                                             float* __restrict__ yH,
                                             float* __restrict__ yV) {
    __shared__ float s_cs[DS];
    __shared__ unsigned long long s_msk[4];
    __shared__ float s_ws[4];
    const int j = threadIdx.x;
    const bool isCol = blockIdx.x >= (NIMG * DS);
    const int line = isCol ? (blockIdx.x - NIMG * DS) : blockIdx.x; // n*256 + (i|c)
    const int n = line >> 8, ic = line & 255;

    size_t src;
    if (!isCol) src = ((size_t)(n * FULL + ic * 8)) * FULL + (size_t)j * 8;
    else        src = ((size_t)(n * FULL + j * 8)) * FULL + (size_t)ic * 8;
    float x = x0[src];
    bool  z = (x1[src] == 0);

    float r = seg_fast(x, z, j, s_cs, s_msk, s_ws);

    if (!isCol) yH[(line << 8) + j] = r;               // coalesced
    else        yV[(n << 16) + (j << 8) + ic] = r;     // scattered 4B into L2 (2MB total)
}

// K3: 8x8 nearest-neighbor upsample of (yH + yV), 32 B nontemporal stores.
__global__ __launch_bounds__(256) void k_up(const float* __restrict__ yH,
                                            const float* __restrict__ yV,
                                            f32x4* __restrict__ out) {
    int gid = blockIdx.x * 256 + threadIdx.x;
    int g2  = gid << 1;          // first of two float4 slots (32 B)
    int j4  = g2 & 511;          // float4 slot within 2048-wide row
    int r   = g2 >> 9;           // n*2048 + I
    int I   = r & 2047;
    int n   = r >> 11;
    int d   = (n << 16) + ((I >> 3) << 8) + (j4 >> 1);
    float v = yH[d] + yV[d];
    f32x4 vv = { v, v, v, v };
    __builtin_nontemporal_store(vv, &out[g2]);
    __builtin_nontemporal_store(vv, &out[g2 + 1]);
}

extern "C" void kernel_launch(void* const* d_in, const int* in_sizes, int n_in,
                              void* d_out, int out_size, void* d_ws, size_t ws_size,
                              hipStream_t stream) {
    const float* x0 = (const float*)d_in[0];
    const int*   x1 = (const int*)d_in[1];
    f32x4* out = (f32x4*)d_out;

    // ws layout: yH (2MB) | yV (2MB)
    float* yH = (float*)d_ws;
    float* yV = yH + NIMG * DS * DS;

    dim3 blk(256);
    k_seg<<<dim3(2 * NIMG * DS), blk, 0, stream>>>(x0, x1, yH, yV);
    k_up <<<dim3(16384),         blk, 0, stream>>>(yH, yV, out);
}

// Round 6
// 76.152 us; speedup vs baseline: 5.6605x; 1.1092x over previous
//
#include <hip/hip_runtime.h>

#define DS   256
#define FULL 2048
#define NIMG 8

typedef float f32x4 __attribute__((ext_vector_type(4)));
typedef int   i32x4 __attribute__((ext_vector_type(4)));

// Segment-mean contribution for a 256-long line handled by 256 threads.
// Returns lr+rl (or 2x where invalid), matching the reference _seg_means.
__device__ __forceinline__ float seg_fast(float x, bool z, int j,
                                          float* s_cs,
                                          unsigned long long* s_msk,
                                          float* s_ws) {
    const int lane = j & 63;
    const int w    = j >> 6;
    unsigned long long m = __ballot(z);

    // wave-level inclusive cumsum in registers
    float s = x;
    #pragma unroll
    for (int off = 1; off < 64; off <<= 1) {
        float t = __shfl_up(s, off, 64);
        if (lane >= off) s += t;
    }
    if (lane == 63) s_ws[w]  = s;
    if (lane == 0)  s_msk[w] = m;
    __syncthreads();

    float pre = 0.f;
    for (int ww = 0; ww < w; ++ww) pre += s_ws[ww];
    s += pre;
    s_cs[j] = s;

    // prev = last boundary < j ; nxt = first boundary > j
    unsigned long long lo = m & ((1ULL << lane) - 1ULL);
    int prev = -1;
    if (lo) prev = (w << 6) + 63 - __builtin_clzll(lo);
    else {
        for (int ww = w - 1; ww >= 0; --ww) {
            unsigned long long mm = s_msk[ww];
            if (mm) { prev = (ww << 6) + 63 - __builtin_clzll(mm); break; }
        }
    }
    unsigned long long hi = m & ~((2ULL << lane) - 1ULL);
    int nxt = DS;
    if (hi) nxt = (w << 6) + __builtin_ctzll(hi);
    else {
        for (int ww = w + 1; ww < 4; ++ww) {
            unsigned long long mm = s_msk[ww];
            if (mm) { nxt = (ww << 6) + __builtin_ctzll(mm); break; }
        }
    }
    __syncthreads();   // s_cs fully written

    bool valid = (!z) && (prev >= 0) && (nxt < DS);
    if (valid) {
        float cs_j   = s_cs[j];
        float cs_pm1 = (prev > 0) ? s_cs[prev - 1] : 0.f;
        float cs_n   = s_cs[nxt];
        float cs_jm1 = (j > 0) ? s_cs[j - 1] : 0.f;
        return (cs_j - cs_pm1) / (float)(j - prev + 1)
             + (cs_n - cs_jm1) / (float)(nxt - j + 1);
    }
    return 2.f * x;
}

// K1: one downsampled row per block. 16B vector gather (element 0 of each
// 32B-strided chunk), horizontal scan, coalesced yH write, TRANSPOSED
// (scattered, fire-and-forget) xzT write so K2 can read coalesced.
__global__ __launch_bounds__(256) void k_row(const float* __restrict__ x0,
                                             const int* __restrict__ x1,
                                             float2* __restrict__ xzT,
                                             float* __restrict__ yH) {
    __shared__ float s_cs[DS];
    __shared__ unsigned long long s_msk[4];
    __shared__ float s_ws[4];
    const int j = threadIdx.x;
    const int line = blockIdx.x;            // n*256 + i
    const int n = line >> 8, i = line & 255;

    size_t rowbase = (size_t)(n * FULL + i * 8) * FULL;
    f32x4 xv = __builtin_nontemporal_load((const f32x4*)(x0 + rowbase + (size_t)j * 8));
    i32x4 iv = __builtin_nontemporal_load((const i32x4*)(x1 + rowbase + (size_t)j * 8));
    float x = xv[0];
    bool  z = (iv[0] == 0);

    float r = seg_fast(x, z, j, s_cs, s_msk, s_ws);

    yH[(line << 8) + j] = r;                        // coalesced
    xzT[(n << 16) + (j << 8) + i] = make_float2(x, z ? 1.f : 0.f);  // transpose scatter
}

// K2: one downsampled column per block. Coalesced float2 read of xzT,
// vertical scan, scattered (fire-and-forget) 4B write into row-major yV.
__global__ __launch_bounds__(256) void k_col(const float2* __restrict__ xzT,
                                             float* __restrict__ yV) {
    __shared__ float s_cs[DS];
    __shared__ unsigned long long s_msk[4];
    __shared__ float s_ws[4];
    const int r = threadIdx.x;
    const int line = blockIdx.x;            // n*256 + c
    const int n = line >> 8, c = line & 255;

    float2 v = xzT[(n << 16) + (c << 8) + r];       // coalesced
    float res = seg_fast(v.x, v.y != 0.f, r, s_cs, s_msk, s_ws);
    yV[(n << 16) + (r << 8) + c] = res;             // row-major scatter
}

// K3: 8x8 nearest-neighbor upsample of (yH + yV), 32 B nontemporal stores.
__global__ __launch_bounds__(256) void k_up(const float* __restrict__ yH,
                                            const float* __restrict__ yV,
                                            f32x4* __restrict__ out) {
    int gid = blockIdx.x * 256 + threadIdx.x;
    int g2  = gid << 1;          // first of two float4 slots (32 B)
    int j4  = g2 & 511;          // float4 slot within 2048-wide row
    int r   = g2 >> 9;           // n*2048 + I
    int I   = r & 2047;
    int n   = r >> 11;
    int d   = (n << 16) + ((I >> 3) << 8) + (j4 >> 1);
    float v = yH[d] + yV[d];
    f32x4 vv = { v, v, v, v };
    __builtin_nontemporal_store(vv, &out[g2]);
    __builtin_nontemporal_store(vv, &out[g2 + 1]);
}

extern "C" void kernel_launch(void* const* d_in, const int* in_sizes, int n_in,
                              void* d_out, int out_size, void* d_ws, size_t ws_size,
                              hipStream_t stream) {
    const float* x0 = (const float*)d_in[0];
    const int*   x1 = (const int*)d_in[1];
    f32x4* out = (f32x4*)d_out;

    // ws layout: xzT (4MB float2, transposed) | yH (2MB) | yV (2MB)
    float2* xzT = (float2*)d_ws;
    float*  yH  = (float*)(xzT + NIMG * DS * DS);
    float*  yV  = yH + NIMG * DS * DS;

    dim3 blk(256);
    k_row<<<dim3(NIMG * DS), blk, 0, stream>>>(x0, x1, xzT, yH);
    k_col<<<dim3(NIMG * DS), blk, 0, stream>>>(xzT, yV);
    k_up <<<dim3(16384),     blk, 0, stream>>>(yH, yV, out);
}

// Round 7
// 48.889 us; speedup vs baseline: 8.8170x; 1.5576x over previous
//
#include <hip/hip_runtime.h>

#define DS   256
#define FULL 2048
#define NIMG 8
#define CG   4      // columns per k_col block

typedef float f32x4 __attribute__((ext_vector_type(4)));
typedef int   i32x4 __attribute__((ext_vector_type(4)));

// Segment-mean contribution for a 256-long line handled by 256 threads.
// Returns lr+rl (or 2x where invalid), matching the reference _seg_means.
// Safe to call back-to-back (internal barriers cover the reuse hazards).
__device__ __forceinline__ float seg_fast(float x, bool z, int j,
                                          float* s_cs,
                                          unsigned long long* s_msk,
                                          float* s_ws) {
    const int lane = j & 63;
    const int w    = j >> 6;
    unsigned long long m = __ballot(z);

    float s = x;
    #pragma unroll
    for (int off = 1; off < 64; off <<= 1) {
        float t = __shfl_up(s, off, 64);
        if (lane >= off) s += t;
    }
    if (lane == 63) s_ws[w]  = s;
    if (lane == 0)  s_msk[w] = m;
    __syncthreads();

    float pre = 0.f;
    for (int ww = 0; ww < w; ++ww) pre += s_ws[ww];
    s += pre;
    s_cs[j] = s;

    unsigned long long lo = m & ((1ULL << lane) - 1ULL);
    int prev = -1;
    if (lo) prev = (w << 6) + 63 - __builtin_clzll(lo);
    else {
        for (int ww = w - 1; ww >= 0; --ww) {
            unsigned long long mm = s_msk[ww];
            if (mm) { prev = (ww << 6) + 63 - __builtin_clzll(mm); break; }
        }
    }
    unsigned long long hi = m & ~((2ULL << lane) - 1ULL);
    int nxt = DS;
    if (hi) nxt = (w << 6) + __builtin_ctzll(hi);
    else {
        for (int ww = w + 1; ww < 4; ++ww) {
            unsigned long long mm = s_msk[ww];
            if (mm) { nxt = (ww << 6) + __builtin_ctzll(mm); break; }
        }
    }
    __syncthreads();   // s_cs fully written

    bool valid = (!z) && (prev >= 0) && (nxt < DS);
    if (valid) {
        float cs_j   = s_cs[j];
        float cs_pm1 = (prev > 0) ? s_cs[prev - 1] : 0.f;
        float cs_n   = s_cs[nxt];
        float cs_jm1 = (j > 0) ? s_cs[j - 1] : 0.f;
        return (cs_j - cs_pm1) / (float)(j - prev + 1)
             + (cs_n - cs_jm1) / (float)(nxt - j + 1);
    }
    return 2.f * x;
}

// K1: one downsampled row per block. CONTIGUOUS row reads (2x dwordx4 per
// thread per array), LDS redistribution of the stride-8 samples, scan,
// coalesced yH + xz writes.
__global__ __launch_bounds__(256) void k_row(const float* __restrict__ x0,
                                             const int* __restrict__ x1,
                                             float2* __restrict__ xz,
                                             float* __restrict__ yH) {
    __shared__ float s_xf[DS];
    __shared__ float s_zf[DS];
    __shared__ float s_cs[DS];
    __shared__ unsigned long long s_msk[4];
    __shared__ float s_ws[4];
    const int j = threadIdx.x;
    const int line = blockIdx.x;            // n*256 + i
    const int n = line >> 8, i = line & 255;

    const float* rb0 = x0 + (size_t)(n * FULL + i * 8) * FULL;
    const int*   rb1 = x1 + (size_t)(n * FULL + i * 8) * FULL;
    // issue all 4 contiguous 16B loads up front (MLP)
    f32x4 a0 = *(const f32x4*)(rb0 + 4 * j);
    f32x4 a1 = *(const f32x4*)(rb0 + 1024 + 4 * j);
    i32x4 b0 = *(const i32x4*)(rb1 + 4 * j);
    i32x4 b1 = *(const i32x4*)(rb1 + 1024 + 4 * j);
    if (!(j & 1)) {                          // even threads hold sample in elem 0
        int s0 = (j >> 1);                   // round 0: samples [0,128)
        int s1 = 128 + (j >> 1);             // round 1: samples [128,256)
        s_xf[s0] = a0[0];  s_zf[s0] = (b0[0] == 0) ? 1.f : 0.f;
        s_xf[s1] = a1[0];  s_zf[s1] = (b1[0] == 0) ? 1.f : 0.f;
    }
    __syncthreads();

    float x = s_xf[j];
    bool  z = (s_zf[j] != 0.f);
    float r = seg_fast(x, z, j, s_cs, s_msk, s_ws);

    yH[(line << 8) + j] = r;                         // coalesced
    xz[(line << 8) + j] = make_float2(x, z ? 1.f : 0.f);  // coalesced
}

// K2: CG columns per block. Line-granular loads (thread=row reads its 4-col
// 32B segment), LDS transpose, CG sequential scans, 16B contiguous RMW.
__global__ __launch_bounds__(256) void k_col(const float2* __restrict__ xz,
                                             float* __restrict__ yH) {
    __shared__ float s_x[CG][DS];
    __shared__ float s_z[CG][DS];
    __shared__ float s_y[CG][DS];
    __shared__ float s_cs[DS];
    __shared__ unsigned long long s_msk[4];
    __shared__ float s_ws[4];
    const int t = threadIdx.x;               // row
    const int g = blockIdx.x;                // n*64 + colgroup
    const int n = g >> 6, c0 = (g & 63) * CG;

    const float2* base = xz + (n << 16) + (t << 8) + c0;
    f32x4 v0 = *(const f32x4*)(base);        // (x,z) for c0, c0+1
    f32x4 v1 = *(const f32x4*)(base + 2);    // (x,z) for c0+2, c0+3
    s_x[0][t] = v0[0]; s_z[0][t] = v0[1];
    s_x[1][t] = v0[2]; s_z[1][t] = v0[3];
    s_x[2][t] = v1[0]; s_z[2][t] = v1[1];
    s_x[3][t] = v1[2]; s_z[3][t] = v1[3];
    // no barrier needed: each thread reads back only its own writes;
    // cross-thread LDS ordering is handled inside seg_fast.

    #pragma unroll
    for (int c = 0; c < CG; ++c) {
        float x = s_x[c][t];
        bool  z = (s_z[c][t] != 0.f);
        s_y[c][t] = seg_fast(x, z, t, s_cs, s_msk, s_ws);
    }

    float* dst = yH + (n << 16) + (t << 8) + c0;
    f32x4 acc = *(const f32x4*)dst;
    acc[0] += s_y[0][t]; acc[1] += s_y[1][t];
    acc[2] += s_y[2][t]; acc[3] += s_y[3][t];
    *(f32x4*)dst = acc;                      // 16B contiguous per thread
}

// K3: 8x8 nearest-neighbor upsample of yH, 32B per thread coalesced stores.
__global__ __launch_bounds__(256) void k_up(const float* __restrict__ yH,
                                            f32x4* __restrict__ out) {
    int gid = blockIdx.x * 256 + threadIdx.x;
    int g2  = gid << 1;          // first of two float4 slots (32 B)
    int j4  = g2 & 511;          // float4 slot within 2048-wide row
    int r   = g2 >> 9;           // n*2048 + I
    int I   = r & 2047;
    int n   = r >> 11;
    float v = yH[(n << 16) + ((I >> 3) << 8) + (j4 >> 1)];
    f32x4 vv = { v, v, v, v };
    out[g2]     = vv;
    out[g2 + 1] = vv;
}

extern "C" void kernel_launch(void* const* d_in, const int* in_sizes, int n_in,
                              void* d_out, int out_size, void* d_ws, size_t ws_size,
                              hipStream_t stream) {
    const float* x0 = (const float*)d_in[0];
    const int*   x1 = (const int*)d_in[1];
    f32x4* out = (f32x4*)d_out;

    // ws layout: xz (4MB float2) | yH (2MB)
    float2* xz = (float2*)d_ws;
    float*  yH = (float*)(xz + NIMG * DS * DS);

    dim3 blk(256);
    k_row<<<dim3(NIMG * DS),      blk, 0, stream>>>(x0, x1, xz, yH);
    k_col<<<dim3(NIMG * DS / CG), blk, 0, stream>>>(xz, yH);
    k_up <<<dim3(16384),          blk, 0, stream>>>(yH, out);
}

// Round 8
// 47.098 us; speedup vs baseline: 9.1522x; 1.0380x over previous
//
#include <hip/hip_runtime.h>

#define DS   256
#define FULL 2048
#define NIMG 8
#define CG   4      // columns per k_colup block

typedef float f32x4 __attribute__((ext_vector_type(4)));
typedef int   i32x4 __attribute__((ext_vector_type(4)));

// Segment-mean contribution for a 256-long line handled by 256 threads.
// Returns lr+rl (or 2x where invalid), matching the reference _seg_means.
// Safe to call back-to-back (internal barriers cover the reuse hazards).
__device__ __forceinline__ float seg_fast(float x, bool z, int j,
                                          float* s_cs,
                                          unsigned long long* s_msk,
                                          float* s_ws) {
    const int lane = j & 63;
    const int w    = j >> 6;
    unsigned long long m = __ballot(z);

    float s = x;
    #pragma unroll
    for (int off = 1; off < 64; off <<= 1) {
        float t = __shfl_up(s, off, 64);
        if (lane >= off) s += t;
    }
    if (lane == 63) s_ws[w]  = s;
    if (lane == 0)  s_msk[w] = m;
    __syncthreads();

    float pre = 0.f;
    for (int ww = 0; ww < w; ++ww) pre += s_ws[ww];
    s += pre;
    s_cs[j] = s;

    unsigned long long lo = m & ((1ULL << lane) - 1ULL);
    int prev = -1;
    if (lo) prev = (w << 6) + 63 - __builtin_clzll(lo);
    else {
        for (int ww = w - 1; ww >= 0; --ww) {
            unsigned long long mm = s_msk[ww];
            if (mm) { prev = (ww << 6) + 63 - __builtin_clzll(mm); break; }
        }
    }
    unsigned long long hi = m & ~((2ULL << lane) - 1ULL);
    int nxt = DS;
    if (hi) nxt = (w << 6) + __builtin_ctzll(hi);
    else {
        for (int ww = w + 1; ww < 4; ++ww) {
            unsigned long long mm = s_msk[ww];
            if (mm) { nxt = (ww << 6) + __builtin_ctzll(mm); break; }
        }
    }
    __syncthreads();   // s_cs fully written

    bool valid = (!z) && (prev >= 0) && (nxt < DS);
    if (valid) {
        float cs_j   = s_cs[j];
        float cs_pm1 = (prev > 0) ? s_cs[prev - 1] : 0.f;
        float cs_n   = s_cs[nxt];
        float cs_jm1 = (j > 0) ? s_cs[j - 1] : 0.f;
        return (cs_j - cs_pm1) / (float)(j - prev + 1)
             + (cs_n - cs_jm1) / (float)(nxt - j + 1);
    }
    return 2.f * x;
}

// K_A: one downsampled row per block. Contiguous nontemporal row reads,
// LDS redistribution of stride-8 samples, scan, coalesced yH + xz writes.
__global__ __launch_bounds__(256) void k_row(const float* __restrict__ x0,
                                             const int* __restrict__ x1,
                                             float2* __restrict__ xz,
                                             float* __restrict__ yH) {
    __shared__ float s_xf[DS];
    __shared__ float s_zf[DS];
    __shared__ float s_cs[DS];
    __shared__ unsigned long long s_msk[4];
    __shared__ float s_ws[4];
    const int j = threadIdx.x;
    const int line = blockIdx.x;            // n*256 + i
    const int n = line >> 8, i = line & 255;

    const float* rb0 = x0 + (size_t)(n * FULL + i * 8) * FULL;
    const int*   rb1 = x1 + (size_t)(n * FULL + i * 8) * FULL;
    f32x4 a0 = __builtin_nontemporal_load((const f32x4*)(rb0 + 4 * j));
    f32x4 a1 = __builtin_nontemporal_load((const f32x4*)(rb0 + 1024 + 4 * j));
    i32x4 b0 = __builtin_nontemporal_load((const i32x4*)(rb1 + 4 * j));
    i32x4 b1 = __builtin_nontemporal_load((const i32x4*)(rb1 + 1024 + 4 * j));
    if (!(j & 1)) {                          // even threads hold sample in elem 0
        int s0 = (j >> 1);                   // samples [0,128)
        int s1 = 128 + (j >> 1);             // samples [128,256)
        s_xf[s0] = a0[0];  s_zf[s0] = (b0[0] == 0) ? 1.f : 0.f;
        s_xf[s1] = a1[0];  s_zf[s1] = (b1[0] == 0) ? 1.f : 0.f;
    }
    __syncthreads();

    float x = s_xf[j];
    bool  z = (s_zf[j] != 0.f);
    float r = seg_fast(x, z, j, s_cs, s_msk, s_ws);

    yH[(line << 8) + j] = r;                              // coalesced
    xz[(line << 8) + j] = make_float2(x, z ? 1.f : 0.f);  // coalesced
}

// K_B: (image, 4-column group) per block. Coalesced xz/yH reads, LDS
// transpose, 4 vertical scans, then DIRECT 8x8-upsampled output write:
// 2048 rows x 128B aligned nontemporal segments for this block's 32 columns.
__global__ __launch_bounds__(256) void k_colup(const float2* __restrict__ xz,
                                               const float* __restrict__ yH,
                                               f32x4* __restrict__ out) {
    __shared__ float s_x[CG][DS];
    __shared__ float s_z[CG][DS];
    __shared__ float s_out[CG][DS + 1];      // +1 pad: conflict-free col reads
    __shared__ float s_cs[DS];
    __shared__ unsigned long long s_msk[4];
    __shared__ float s_ws[4];
    const int t = threadIdx.x;               // downsampled row
    const int g = blockIdx.x;                // n*64 + colgroup
    const int n = g >> 6, c0 = (g & 63) * CG;

    const float2* base = xz + (n << 16) + (t << 8) + c0;
    f32x4 v0 = *(const f32x4*)(base);        // (x,z) for c0, c0+1
    f32x4 v1 = *(const f32x4*)(base + 2);    // (x,z) for c0+2, c0+3
    f32x4 h  = *(const f32x4*)(yH + (n << 16) + (t << 8) + c0);
    s_x[0][t] = v0[0]; s_z[0][t] = v0[1];
    s_x[1][t] = v0[2]; s_z[1][t] = v0[3];
    s_x[2][t] = v1[0]; s_z[2][t] = v1[1];
    s_x[3][t] = v1[2]; s_z[3][t] = v1[3];
    // no barrier needed: each thread reads back only its own s_x/s_z entries.

    #pragma unroll
    for (int c = 0; c < CG; ++c) {
        float x = s_x[c][t];
        bool  z = (s_z[c][t] != 0.f);
        float r = seg_fast(x, z, t, s_cs, s_msk, s_ws);
        s_out[c][t] = r + h[c];              // vertical + horizontal
    }
    __syncthreads();                         // s_out complete

    // Upsampled write: 2048 output rows x 8 f32x4 slots (32 cols).
    f32x4* ob = out + ((size_t)n << 20) + (c0 << 1);
    #pragma unroll 4
    for (int k = 0; k < 64; ++k) {
        int idx = (k << 8) + t;              // 0..16383
        int I   = idx >> 3;                  // output row
        int s   = idx & 7;                   // f32x4 slot within 128B segment
        float v = s_out[s >> 1][I >> 3];
        f32x4 vv = { v, v, v, v };
        __builtin_nontemporal_store(vv, ob + (size_t)I * 512 + s);
    }
}

extern "C" void kernel_launch(void* const* d_in, const int* in_sizes, int n_in,
                              void* d_out, int out_size, void* d_ws, size_t ws_size,
                              hipStream_t stream) {
    const float* x0 = (const float*)d_in[0];
    const int*   x1 = (const int*)d_in[1];
    f32x4* out = (f32x4*)d_out;

    // ws layout: xz (4MB float2) | yH (2MB)
    float2* xz = (float2*)d_ws;
    float*  yH = (float*)(xz + NIMG * DS * DS);

    dim3 blk(256);
    k_row  <<<dim3(NIMG * DS),      blk, 0, stream>>>(x0, x1, xz, yH);
    k_colup<<<dim3(NIMG * DS / CG), blk, 0, stream>>>(xz, yH, out);
}

// Round 9
// 44.454 us; speedup vs baseline: 9.6967x; 1.0595x over previous
//
#include <hip/hip_runtime.h>

#define DS   256
#define FULL 2048
#define NIMG 8
#define CG   4      // columns per k_colup block

typedef float f32x4 __attribute__((ext_vector_type(4)));
typedef int   i32x4 __attribute__((ext_vector_type(4)));

// Segment-mean contribution for a 256-long line handled by 256 threads.
// Returns lr+rl (or 2x where invalid), matching the reference _seg_means.
// Safe to call back-to-back (internal barriers cover the reuse hazards).
__device__ __forceinline__ float seg_fast(float x, bool z, int j,
                                          float* s_cs,
                                          unsigned long long* s_msk,
                                          float* s_ws) {
    const int lane = j & 63;
    const int w    = j >> 6;
    unsigned long long m = __ballot(z);

    float s = x;
    #pragma unroll
    for (int off = 1; off < 64; off <<= 1) {
        float t = __shfl_up(s, off, 64);
        if (lane >= off) s += t;
    }
    if (lane == 63) s_ws[w]  = s;
    if (lane == 0)  s_msk[w] = m;
    __syncthreads();

    float pre = 0.f;
    for (int ww = 0; ww < w; ++ww) pre += s_ws[ww];
    s += pre;
    s_cs[j] = s;

    unsigned long long lo = m & ((1ULL << lane) - 1ULL);
    int prev = -1;
    if (lo) prev = (w << 6) + 63 - __builtin_clzll(lo);
    else {
        for (int ww = w - 1; ww >= 0; --ww) {
            unsigned long long mm = s_msk[ww];
            if (mm) { prev = (ww << 6) + 63 - __builtin_clzll(mm); break; }
        }
    }
    unsigned long long hi = m & ~((2ULL << lane) - 1ULL);
    int nxt = DS;
    if (hi) nxt = (w << 6) + __builtin_ctzll(hi);
    else {
        for (int ww = w + 1; ww < 4; ++ww) {
            unsigned long long mm = s_msk[ww];
            if (mm) { nxt = (ww << 6) + __builtin_ctzll(mm); break; }
        }
    }
    __syncthreads();   // s_cs fully written

    bool valid = (!z) && (prev >= 0) && (nxt < DS);
    if (valid) {
        float cs_j   = s_cs[j];
        float cs_pm1 = (prev > 0) ? s_cs[prev - 1] : 0.f;
        float cs_n   = s_cs[nxt];
        float cs_jm1 = (j > 0) ? s_cs[j - 1] : 0.f;
        return (cs_j - cs_pm1) / (float)(j - prev + 1)
             + (cs_n - cs_jm1) / (float)(nxt - j + 1);
    }
    return 2.f * x;
}

// K_A: one downsampled row per block. Contiguous nontemporal row reads,
// LDS redistribution of stride-8 samples, scan, coalesced yH + xz writes.
__global__ __launch_bounds__(256) void k_row(const float* __restrict__ x0,
                                             const int* __restrict__ x1,
                                             float2* __restrict__ xz,
                                             float* __restrict__ yH) {
    __shared__ float s_xf[DS];
    __shared__ float s_zf[DS];
    __shared__ float s_cs[DS];
    __shared__ unsigned long long s_msk[4];
    __shared__ float s_ws[4];
    const int j = threadIdx.x;
    const int line = blockIdx.x;            // n*256 + i
    const int n = line >> 8, i = line & 255;

    const float* rb0 = x0 + (size_t)(n * FULL + i * 8) * FULL;
    const int*   rb1 = x1 + (size_t)(n * FULL + i * 8) * FULL;
    f32x4 a0 = __builtin_nontemporal_load((const f32x4*)(rb0 + 4 * j));
    f32x4 a1 = __builtin_nontemporal_load((const f32x4*)(rb0 + 1024 + 4 * j));
    i32x4 b0 = __builtin_nontemporal_load((const i32x4*)(rb1 + 4 * j));
    i32x4 b1 = __builtin_nontemporal_load((const i32x4*)(rb1 + 1024 + 4 * j));
    if (!(j & 1)) {                          // even threads hold sample in elem 0
        int s0 = (j >> 1);                   // samples [0,128)
        int s1 = 128 + (j >> 1);             // samples [128,256)
        s_xf[s0] = a0[0];  s_zf[s0] = (b0[0] == 0) ? 1.f : 0.f;
        s_xf[s1] = a1[0];  s_zf[s1] = (b1[0] == 0) ? 1.f : 0.f;
    }
    __syncthreads();

    float x = s_xf[j];
    bool  z = (s_zf[j] != 0.f);
    float r = seg_fast(x, z, j, s_cs, s_msk, s_ws);

    yH[(line << 8) + j] = r;                              // coalesced
    xz[(line << 8) + j] = make_float2(x, z ? 1.f : 0.f);  // coalesced
}

// K_B: (image, 4-column group) per block. Coalesced xz/yH reads, LDS
// transpose, 4 vertical scans, then DIRECT 8x8-upsampled output write:
// 2048 rows x 128B segments, PLAIN stores, 32B contiguous per thread.
__global__ __launch_bounds__(256) void k_colup(const float2* __restrict__ xz,
                                               const float* __restrict__ yH,
                                               f32x4* __restrict__ out) {
    __shared__ float s_x[CG][DS];
    __shared__ float s_z[CG][DS];
    __shared__ float s_out[CG][DS + 1];      // +1 pad: conflict-free col reads
    __shared__ float s_cs[DS];
    __shared__ unsigned long long s_msk[4];
    __shared__ float s_ws[4];
    const int t = threadIdx.x;               // downsampled row
    const int g = blockIdx.x;                // n*64 + colgroup
    const int n = g >> 6, c0 = (g & 63) * CG;

    const float2* base = xz + (n << 16) + (t << 8) + c0;
    f32x4 v0 = *(const f32x4*)(base);        // (x,z) for c0, c0+1
    f32x4 v1 = *(const f32x4*)(base + 2);    // (x,z) for c0+2, c0+3
    f32x4 h  = *(const f32x4*)(yH + (n << 16) + (t << 8) + c0);
    s_x[0][t] = v0[0]; s_z[0][t] = v0[1];
    s_x[1][t] = v0[2]; s_z[1][t] = v0[3];
    s_x[2][t] = v1[0]; s_z[2][t] = v1[1];
    s_x[3][t] = v1[2]; s_z[3][t] = v1[3];
    // no barrier needed: each thread reads back only its own s_x/s_z entries.

    #pragma unroll
    for (int c = 0; c < CG; ++c) {
        float x = s_x[c][t];
        bool  z = (s_z[c][t] != 0.f);
        float r = seg_fast(x, z, t, s_cs, s_msk, s_ws);
        s_out[c][t] = r + h[c];              // vertical + horizontal
    }
    __syncthreads();                         // s_out complete

    // Upsampled write: 2048 output rows x 8 f32x4 slots (32 cols).
    // Each thread: two consecutive f32x4 (32B) per iteration, plain stores.
    f32x4* ob = out + ((size_t)n << 20) + (c0 << 1);
    #pragma unroll 4
    for (int k = 0; k < 32; ++k) {
        int idx = (k << 8) + t;              // 0..8191 (pair index)
        int I   = idx >> 2;                  // output row
        int c   = idx & 3;                   // downsampled column within group
        float v = s_out[c][I >> 3];
        f32x4 vv = { v, v, v, v };
        size_t o = (size_t)I * 512 + (c << 1);
        ob[o]     = vv;
        ob[o + 1] = vv;
    }
}

extern "C" void kernel_launch(void* const* d_in, const int* in_sizes, int n_in,
                              void* d_out, int out_size, void* d_ws, size_t ws_size,
                              hipStream_t stream) {
    const float* x0 = (const float*)d_in[0];
    const int*   x1 = (const int*)d_in[1];
    f32x4* out = (f32x4*)d_out;

    // ws layout: xz (4MB float2) | yH (2MB)
    float2* xz = (float2*)d_ws;
    float*  yH = (float*)(xz + NIMG * DS * DS);

    dim3 blk(256);
    k_row  <<<dim3(NIMG * DS),      blk, 0, stream>>>(x0, x1, xz, yH);
    k_colup<<<dim3(NIMG * DS / CG), blk, 0, stream>>>(xz, yH, out);
}

// Round 10
// 43.461 us; speedup vs baseline: 9.9183x; 1.0229x over previous
//
#include <hip/hip_runtime.h>

#define DS   256
#define FULL 2048
#define NIMG 8
#define CG   4      // columns per k_colup block

typedef float f32x4 __attribute__((ext_vector_type(4)));
typedef int   i32x4 __attribute__((ext_vector_type(4)));

// Segment-mean contribution for a 256-long line handled by 256 threads.
// Returns lr+rl (or 2x where invalid), matching the reference _seg_means.
// Safe to call back-to-back (internal barriers cover the reuse hazards).
__device__ __forceinline__ float seg_fast(float x, bool z, int j,
                                          float* s_cs,
                                          unsigned long long* s_msk,
                                          float* s_ws) {
    const int lane = j & 63;
    const int w    = j >> 6;
    unsigned long long m = __ballot(z);

    float s = x;
    #pragma unroll
    for (int off = 1; off < 64; off <<= 1) {
        float t = __shfl_up(s, off, 64);
        if (lane >= off) s += t;
    }
    if (lane == 63) s_ws[w]  = s;
    if (lane == 0)  s_msk[w] = m;
    __syncthreads();

    float pre = 0.f;
    for (int ww = 0; ww < w; ++ww) pre += s_ws[ww];
    s += pre;
    s_cs[j] = s;

    unsigned long long lo = m & ((1ULL << lane) - 1ULL);
    int prev = -1;
    if (lo) prev = (w << 6) + 63 - __builtin_clzll(lo);
    else {
        for (int ww = w - 1; ww >= 0; --ww) {
            unsigned long long mm = s_msk[ww];
            if (mm) { prev = (ww << 6) + 63 - __builtin_clzll(mm); break; }
        }
    }
    unsigned long long hi = m & ~((2ULL << lane) - 1ULL);
    int nxt = DS;
    if (hi) nxt = (w << 6) + __builtin_ctzll(hi);
    else {
        for (int ww = w + 1; ww < 4; ++ww) {
            unsigned long long mm = s_msk[ww];
            if (mm) { nxt = (ww << 6) + __builtin_ctzll(mm); break; }
        }
    }
    __syncthreads();   // s_cs fully written

    bool valid = (!z) && (prev >= 0) && (nxt < DS);
    if (valid) {
        float cs_j   = s_cs[j];
        float cs_pm1 = (prev > 0) ? s_cs[prev - 1] : 0.f;
        float cs_n   = s_cs[nxt];
        float cs_jm1 = (j > 0) ? s_cs[j - 1] : 0.f;
        return (cs_j - cs_pm1) / (float)(j - prev + 1)
             + (cs_n - cs_jm1) / (float)(nxt - j + 1);
    }
    return 2.f * x;
}

// K_A: one downsampled row per block. Thread j loads the 16B chunk that
// CONTAINS sample j (byte 32j, elem 0) -> 2 loads/thread, no LDS exchange.
// Same HBM lines touched (every 64B line holds 2 samples regardless).
__global__ __launch_bounds__(256) void k_row(const float* __restrict__ x0,
                                             const int* __restrict__ x1,
                                             float2* __restrict__ xz,
                                             float* __restrict__ yH) {
    __shared__ float s_cs[DS];
    __shared__ unsigned long long s_msk[4];
    __shared__ float s_ws[4];
    const int j = threadIdx.x;
    const int line = blockIdx.x;            // n*256 + i
    const int n = line >> 8, i = line & 255;

    const float* rb0 = x0 + (size_t)(n * FULL + i * 8) * FULL;
    const int*   rb1 = x1 + (size_t)(n * FULL + i * 8) * FULL;
    f32x4 a = __builtin_nontemporal_load((const f32x4*)(rb0 + 8 * (size_t)j));
    i32x4 b = __builtin_nontemporal_load((const i32x4*)(rb1 + 8 * (size_t)j));
    float x = a[0];
    bool  z = (b[0] == 0);

    float r = seg_fast(x, z, j, s_cs, s_msk, s_ws);

    yH[(line << 8) + j] = r;                              // coalesced
    xz[(line << 8) + j] = make_float2(x, z ? 1.f : 0.f);  // coalesced
}

// K_B: (image, colgroup, row-half) per block — 1024 blocks (4/CU).
// Both row-half blocks redundantly run the cheap 4-column scans; each
// writes only its half of the upsampled rows (doubled write concurrency,
// same 128B-segment pattern that measured best).
__global__ __launch_bounds__(256) void k_colup(const float2* __restrict__ xz,
                                               const float* __restrict__ yH,
                                               f32x4* __restrict__ out) {
    __shared__ float s_x[CG][DS];
    __shared__ float s_z[CG][DS];
    __shared__ float s_out[CG][DS + 1];      // +1 pad: conflict-free col reads
    __shared__ float s_cs[DS];
    __shared__ unsigned long long s_msk[4];
    __shared__ float s_ws[4];
    const int t = threadIdx.x;               // downsampled row
    const int g = blockIdx.x;                // n*128 + rowhalf*64 + colgroup
    const int n  = g >> 7;
    const int q  = (g >> 6) & 1;             // which half of output rows
    const int c0 = (g & 63) * CG;

    const float2* base = xz + (n << 16) + (t << 8) + c0;
    f32x4 v0 = *(const f32x4*)(base);        // (x,z) for c0, c0+1
    f32x4 v1 = *(const f32x4*)(base + 2);    // (x,z) for c0+2, c0+3
    f32x4 h  = *(const f32x4*)(yH + (n << 16) + (t << 8) + c0);
    s_x[0][t] = v0[0]; s_z[0][t] = v0[1];
    s_x[1][t] = v0[2]; s_z[1][t] = v0[3];
    s_x[2][t] = v1[0]; s_z[2][t] = v1[1];
    s_x[3][t] = v1[2]; s_z[3][t] = v1[3];
    // no barrier needed: each thread reads back only its own s_x/s_z entries.

    #pragma unroll
    for (int c = 0; c < CG; ++c) {
        float x = s_x[c][t];
        bool  z = (s_z[c][t] != 0.f);
        float r = seg_fast(x, z, t, s_cs, s_msk, s_ws);
        s_out[c][t] = r + h[c];              // vertical + horizontal
    }
    __syncthreads();                         // s_out complete

    // This block's half: 1024 output rows x 8 f32x4 slots (32 cols).
    // Each thread: two consecutive f32x4 (32B) per iteration, plain stores.
    f32x4* ob = out + ((size_t)n << 20) + (c0 << 1);
    #pragma unroll 4
    for (int k = 0; k < 16; ++k) {
        int idx = (k << 8) + t;              // 0..4095 (pair index)
        int I   = (q << 10) + (idx >> 2);    // output row
        int c   = idx & 3;                   // downsampled column within group
        float v = s_out[c][I >> 3];
        f32x4 vv = { v, v, v, v };
        size_t o = (size_t)I * 512 + (c << 1);
        ob[o]     = vv;
        ob[o + 1] = vv;
    }
}

extern "C" void kernel_launch(void* const* d_in, const int* in_sizes, int n_in,
                              void* d_out, int out_size, void* d_ws, size_t ws_size,
                              hipStream_t stream) {
    const float* x0 = (const float*)d_in[0];
    const int*   x1 = (const int*)d_in[1];
    f32x4* out = (f32x4*)d_out;

    // ws layout: xz (4MB float2) | yH (2MB)
    float2* xz = (float2*)d_ws;
    float*  yH = (float*)(xz + NIMG * DS * DS);

    dim3 blk(256);
    k_row  <<<dim3(NIMG * DS),          blk, 0, stream>>>(x0, x1, xz, yH);
    k_colup<<<dim3(2 * NIMG * DS / CG), blk, 0, stream>>>(xz, yH, out);
}